// Round 1
// baseline (273.442 us; speedup 1.0000x reference)
//
#include <hip/hip_runtime.h>
#include <hip/hip_bf16.h>
#include <math.h>

#define B_  32
#define T_  128
#define NF_ 20
#define D_  512
#define S_  5
#define L_  96
#define EPS_ 1e-8f
#define NSEG (B_ * L_)                       // 3072
#define NPOS (NF_ - 1)                       // 19
#define NNEG ((NF_ - 1) * S_)                // 95
#define NPAIR (NF_ + NPOS + NNEG)            // 134 dot products per segment
#define NELEM (NF_ * D_)                     // 10240 floats = 40 KB

__global__ __launch_bounds__(256) void phoneme_ssl_loss_kernel(
    const float* __restrict__ out,
    const int* __restrict__ batch_idx,
    const int* __restrict__ time_idx,
    const int* __restrict__ neg_idx,
    float* __restrict__ loss_out) {

  __shared__ float seg[NELEM];     // 40 KB staged segment
  __shared__ float dots[NPAIR];    // [0,20): |f|^2, [20,39): pos dots, [39,134): neg dots

  const int n = blockIdx.x;
  const int b = batch_idx[n];
  const int t = time_idx[n];
  const float* __restrict__ src = out + (size_t)(b * T_ + t) * NELEM;

  // ---- stage 40 KB contiguous segment into LDS, float4 coalesced ----
  const float4* __restrict__ src4 = (const float4*)src;
  float4* seg4 = (float4*)seg;
#pragma unroll
  for (int i = 0; i < NELEM / 4 / 256; ++i)
    seg4[threadIdx.x + 256 * i] = src4[threadIdx.x + 256 * i];
  __syncthreads();

  // ---- 134 dot products, one per wave per iteration ----
  const int wave = threadIdx.x >> 6;
  const int lane = threadIdx.x & 63;
  for (int p = wave; p < NPAIR; p += 4) {
    int fa, fb;
    if (p < NF_) {                 // squared norms
      fa = p; fb = p;
    } else if (p < NF_ + NPOS) {   // positive: (i, i+1)
      fa = p - NF_; fb = fa + 1;
    } else {                       // negative: (i, neg_idx[i*S+j])
      int q = p - NF_ - NPOS;
      fa = q / S_;
      fb = neg_idx[q];
    }
    const float* __restrict__ va = seg + fa * D_;
    const float* __restrict__ vb = seg + fb * D_;
    float acc = 0.f;
#pragma unroll
    for (int k = 0; k < D_ / 64; ++k)       // lane-strided: bank = lane%32, 2-way free
      acc += va[lane + 64 * k] * vb[lane + 64 * k];
#pragma unroll
    for (int off = 32; off >= 1; off >>= 1)
      acc += __shfl_xor(acc, off, 64);
    if (lane == 0) dots[p] = acc;
  }
  __syncthreads();

  // ---- 19 softmax rows, threads 0..18 ----
  float local = 0.f;
  if (threadIdx.x < NPOS) {
    const int i = threadIdx.x;
    const float na = sqrtf(dots[i]);
    float sims[1 + S_];
    {
      const float nb = sqrtf(dots[i + 1]);
      sims[0] = dots[NF_ + i] / fmaxf(na * nb, EPS_);
    }
#pragma unroll
    for (int j = 0; j < S_; ++j) {
      const int fb = neg_idx[i * S_ + j];
      const float nb = sqrtf(dots[fb]);
      sims[1 + j] = dots[NF_ + NPOS + i * S_ + j] / fmaxf(na * nb, EPS_);
    }
    float m = sims[0];
#pragma unroll
    for (int j = 1; j < 1 + S_; ++j) m = fmaxf(m, sims[j]);
    float se = 0.f;
#pragma unroll
    for (int j = 0; j < 1 + S_; ++j) se += __expf(sims[j] - m);
    const float lse = m + __logf(se);
    local = -(sims[0] - lse);      // -log_softmax[...,0]
  }

  // ---- block reduce (all contributors are in wave 0) + one atomic ----
  if (threadIdx.x < 64) {
#pragma unroll
    for (int off = 32; off >= 1; off >>= 1)
      local += __shfl_xor(local, off, 64);
    if (threadIdx.x == 0)
      atomicAdd(loss_out, local * (1.0f / (float)(NSEG * NPOS)));
  }
}

extern "C" void kernel_launch(void* const* d_in, const int* in_sizes, int n_in,
                              void* d_out, int out_size, void* d_ws, size_t ws_size,
                              hipStream_t stream) {
  const float* out_t    = (const float*)d_in[0];
  const int* batch_idx  = (const int*)d_in[1];
  const int* time_idx   = (const int*)d_in[2];
  const int* neg_idx    = (const int*)d_in[3];
  float* loss_out       = (float*)d_out;

  // d_out is poisoned before every timed launch; zero it (graph-capture safe).
  hipMemsetAsync(loss_out, 0, sizeof(float), stream);

  phoneme_ssl_loss_kernel<<<NSEG, 256, 0, stream>>>(
      out_t, batch_idx, time_idx, neg_idx, loss_out);
}

// Round 2
// 234.428 us; speedup vs baseline: 1.1664x; 1.1664x over previous
//
#include <hip/hip_runtime.h>
#include <hip/hip_bf16.h>
#include <math.h>

#define B_  32
#define T_  128
#define NF_ 20
#define D_  512
#define S_  5
#define L_  96
#define EPS_ 1e-8f
#define NSEG (B_ * L_)                       // 3072
#define NPOS (NF_ - 1)                       // 19
#define NELEM (NF_ * D_)                     // 10240 floats = 40 KB
#define RPAD (D_ + 8)                        // padded row (shorts): breaks pow2 bank stride
#define GLD 33                               // Gram leading dim (fp32)

typedef short short8 __attribute__((ext_vector_type(8)));
typedef float f32x4  __attribute__((ext_vector_type(4)));

__device__ __forceinline__ unsigned short f2bf(float f) {
  unsigned int u = __float_as_uint(f);
  u += 0x7fffu + ((u >> 16) & 1u);           // round-to-nearest-even
  return (unsigned short)(u >> 16);
}

__global__ __launch_bounds__(256) void phoneme_ssl_loss_kernel(
    const float* __restrict__ out,
    const int* __restrict__ batch_idx,
    const int* __restrict__ time_idx,
    const int* __restrict__ neg_idx,
    float* __restrict__ loss_out) {

  __shared__ __align__(16) unsigned short V[NF_ * RPAD];  // 20 rows x 520 bf16 = 20800 B
  __shared__ float G[32 * GLD];                           // 32x32 Gram, stride 33 = 4224 B

  const int n = blockIdx.x;
  const int b = batch_idx[n];
  const int t = time_idx[n];
  const float* __restrict__ src = out + (size_t)(b * T_ + t) * NELEM;

  // ---- stage: fp32 global -> bf16 LDS, 8 floats (32 B) per thread-iter ----
  const float4* __restrict__ src4 = (const float4*)src;
#pragma unroll
  for (int it = 0; it < 5; ++it) {           // 1280 chunks of 8 floats / 256 threads
    const int c = threadIdx.x + 256 * it;
    const float4 x = src4[2 * c];
    const float4 y = src4[2 * c + 1];
    short8 v;
    v[0] = (short)f2bf(x.x); v[1] = (short)f2bf(x.y);
    v[2] = (short)f2bf(x.z); v[3] = (short)f2bf(x.w);
    v[4] = (short)f2bf(y.x); v[5] = (short)f2bf(y.y);
    v[6] = (short)f2bf(y.z); v[7] = (short)f2bf(y.w);
    const int row = c >> 6;                  // 64 chunks (512 bf16) per row
    const int col = (c & 63) * 8;
    *(short8*)&V[row * RPAD + col] = v;      // ds_write_b128
  }
  __syncthreads();

  // ---- Gram via MFMA (wave 0 only): G = V * V^T, 2x2 tiles of 16x16x32 ----
  if (threadIdx.x < 64) {
    const int lane = threadIdx.x;
    const int r = lane & 15;
    const int q = lane >> 4;                 // quad: k = q*8 + j
    const int row1 = (16 + r > 19) ? 19 : 16 + r;  // clamp; rows >=20 unused in output
    const unsigned short* p0 = &V[r    * RPAD + q * 8];
    const unsigned short* p1 = &V[row1 * RPAD + q * 8];
    f32x4 c00 = {0.f, 0.f, 0.f, 0.f}, c01 = c00, c10 = c00, c11 = c00;
#pragma unroll
    for (int ks = 0; ks < D_ / 32; ++ks) {   // 16 K-steps of 32
      const short8 a0 = *(const short8*)(p0 + 32 * ks);   // ds_read_b128
      const short8 a1 = *(const short8*)(p1 + 32 * ks);
      // B fragment == A fragment for Gram (B[k][n] = V[n][k])
      c00 = __builtin_amdgcn_mfma_f32_16x16x32_bf16(a0, a0, c00, 0, 0, 0);
      c01 = __builtin_amdgcn_mfma_f32_16x16x32_bf16(a0, a1, c01, 0, 0, 0);
      c10 = __builtin_amdgcn_mfma_f32_16x16x32_bf16(a1, a0, c10, 0, 0, 0);
      c11 = __builtin_amdgcn_mfma_f32_16x16x32_bf16(a1, a1, c11, 0, 0, 0);
    }
    // C/D layout (verified): col = lane&15, row = (lane>>4)*4 + reg
#pragma unroll
    for (int reg = 0; reg < 4; ++reg) {
      const int rr = q * 4 + reg;
      G[rr        * GLD + r]      = c00[reg];
      G[rr        * GLD + 16 + r] = c01[reg];
      G[(16 + rr) * GLD + r]      = c10[reg];
      G[(16 + rr) * GLD + 16 + r] = c11[reg];
    }
  }
  __syncthreads();

  // ---- softmax rows from Gram, threads 0..18 (all in wave 0) ----
  float local = 0.f;
  if (threadIdx.x < NPOS) {
    const int i = threadIdx.x;
    const float na = sqrtf(G[i * GLD + i]);
    float sims[1 + S_];
    {
      const float nb = sqrtf(G[(i + 1) * GLD + (i + 1)]);
      sims[0] = G[i * GLD + (i + 1)] / fmaxf(na * nb, EPS_);
    }
#pragma unroll
    for (int j = 0; j < S_; ++j) {
      const int f = neg_idx[i * S_ + j];
      const float nb = sqrtf(G[f * GLD + f]);
      sims[1 + j] = G[i * GLD + f] / fmaxf(na * nb, EPS_);
    }
    float m = sims[0];
#pragma unroll
    for (int j = 1; j < 1 + S_; ++j) m = fmaxf(m, sims[j]);
    float se = 0.f;
#pragma unroll
    for (int j = 0; j < 1 + S_; ++j) se += expf(sims[j] - m);
    const float lse = m + logf(se);
    local = -(sims[0] - lse);                // -log_softmax[...,0]
  }

  // ---- wave-0 reduce + one atomic per block ----
  if (threadIdx.x < 64) {
#pragma unroll
    for (int off = 32; off >= 1; off >>= 1)
      local += __shfl_xor(local, off, 64);
    if (threadIdx.x == 0)
      atomicAdd(loss_out, local * (1.0f / (float)(NSEG * NPOS)));
  }
}

extern "C" void kernel_launch(void* const* d_in, const int* in_sizes, int n_in,
                              void* d_out, int out_size, void* d_ws, size_t ws_size,
                              hipStream_t stream) {
  const float* out_t    = (const float*)d_in[0];
  const int* batch_idx  = (const int*)d_in[1];
  const int* time_idx   = (const int*)d_in[2];
  const int* neg_idx    = (const int*)d_in[3];
  float* loss_out       = (float*)d_out;

  hipMemsetAsync(loss_out, 0, sizeof(float), stream);

  phoneme_ssl_loss_kernel<<<NSEG, 256, 0, stream>>>(
      out_t, batch_idx, time_idx, neg_idx, loss_out);
}

// Round 3
// 223.525 us; speedup vs baseline: 1.2233x; 1.0488x over previous
//
#include <hip/hip_runtime.h>
#include <hip/hip_bf16.h>
#include <math.h>

#define B_  32
#define T_  128
#define NF_ 20
#define D_  512
#define S_  5
#define L_  96
#define EPS_ 1e-8f
#define NSEG (B_ * L_)                       // 3072
#define NPOS (NF_ - 1)                       // 19
#define NELEM (NF_ * D_)                     // 10240 floats = 40 KB
#define RPAD (D_ + 8)                        // padded row (shorts): breaks pow2 bank stride
#define GLD 33                               // Gram leading dim (fp32)

typedef short short8 __attribute__((ext_vector_type(8)));
typedef float f32x4  __attribute__((ext_vector_type(4)));

__device__ __forceinline__ unsigned short f2bf(float f) {
  unsigned int u = __float_as_uint(f);
  u += 0x7fffu + ((u >> 16) & 1u);           // round-to-nearest-even
  return (unsigned short)(u >> 16);
}

__global__ __launch_bounds__(256) void phoneme_ssl_seg_kernel(
    const float* __restrict__ out,
    const int* __restrict__ batch_idx,
    const int* __restrict__ time_idx,
    const int* __restrict__ neg_idx,
    float* __restrict__ partials) {

  __shared__ __align__(16) unsigned short V[NF_ * RPAD];  // 20 x 520 bf16 = 20800 B
  __shared__ float G[32 * GLD];                           // 32x32 Gram, stride 33

  const int n = blockIdx.x;
  const int b = batch_idx[n];
  const int t = time_idx[n];
  const float* __restrict__ src = out + (size_t)(b * T_ + t) * NELEM;

  // ---- stage: fp32 global -> bf16 LDS, 8 floats per thread-iter, coalesced ----
  const float4* __restrict__ src4 = (const float4*)src;
#pragma unroll
  for (int it = 0; it < 5; ++it) {           // 1280 chunks of 8 floats / 256 threads
    const int c = threadIdx.x + 256 * it;
    const float4 x = src4[2 * c];
    const float4 y = src4[2 * c + 1];
    short8 v;
    v[0] = (short)f2bf(x.x); v[1] = (short)f2bf(x.y);
    v[2] = (short)f2bf(x.z); v[3] = (short)f2bf(x.w);
    v[4] = (short)f2bf(y.x); v[5] = (short)f2bf(y.y);
    v[6] = (short)f2bf(y.z); v[7] = (short)f2bf(y.w);
    const int row = c >> 6;                  // 64 chunks (512 bf16) per row
    const int col = (c & 63) * 8;
    *(short8*)&V[row * RPAD + col] = v;      // ds_write_b128
  }
  __syncthreads();
  // Waves 1-3 are done: everything below is wave 0 only (no more barriers,
  // G is produced AND consumed by wave 0 — compiler's lgkmcnt handles it).
  if (threadIdx.x >= 64) return;

  // ---- Gram via MFMA: G = V * V^T, 2x2 tiles of 16x16x32 ----
  {
    const int lane = threadIdx.x;
    const int r = lane & 15;
    const int q = lane >> 4;                 // quad: k = q*8 + j
    const int row1 = (16 + r > 19) ? 19 : 16 + r;  // clamp; rows >=20 unused
    const unsigned short* p0 = &V[r    * RPAD + q * 8];
    const unsigned short* p1 = &V[row1 * RPAD + q * 8];
    f32x4 c00 = {0.f, 0.f, 0.f, 0.f}, c01 = c00, c10 = c00, c11 = c00;
#pragma unroll
    for (int ks = 0; ks < D_ / 32; ++ks) {   // 16 K-steps of 32
      const short8 a0 = *(const short8*)(p0 + 32 * ks);   // ds_read_b128
      const short8 a1 = *(const short8*)(p1 + 32 * ks);
      // B fragment == A fragment for Gram (B[k][n] = V[n][k])
      c00 = __builtin_amdgcn_mfma_f32_16x16x32_bf16(a0, a0, c00, 0, 0, 0);
      c01 = __builtin_amdgcn_mfma_f32_16x16x32_bf16(a0, a1, c01, 0, 0, 0);
      c10 = __builtin_amdgcn_mfma_f32_16x16x32_bf16(a1, a0, c10, 0, 0, 0);
      c11 = __builtin_amdgcn_mfma_f32_16x16x32_bf16(a1, a1, c11, 0, 0, 0);
    }
    // C/D layout (verified): col = lane&15, row = (lane>>4)*4 + reg
#pragma unroll
    for (int reg = 0; reg < 4; ++reg) {
      const int rr = q * 4 + reg;
      G[rr        * GLD + r]      = c00[reg];
      G[rr        * GLD + 16 + r] = c01[reg];
      G[(16 + rr) * GLD + r]      = c10[reg];
      G[(16 + rr) * GLD + 16 + r] = c11[reg];
    }
  }

  // ---- softmax rows from Gram, lanes 0..18 ----
  float local = 0.f;
  if (threadIdx.x < NPOS) {
    const int i = threadIdx.x;
    const float na = sqrtf(G[i * GLD + i]);
    float sims[1 + S_];
    {
      const float nb = sqrtf(G[(i + 1) * GLD + (i + 1)]);
      sims[0] = G[i * GLD + (i + 1)] / fmaxf(na * nb, EPS_);
    }
#pragma unroll
    for (int j = 0; j < S_; ++j) {
      const int f = neg_idx[i * S_ + j];
      const float nb = sqrtf(G[f * GLD + f]);
      sims[1 + j] = G[i * GLD + f] / fmaxf(na * nb, EPS_);
    }
    float m = sims[0];
#pragma unroll
    for (int j = 1; j < 1 + S_; ++j) m = fmaxf(m, sims[j]);
    float se = 0.f;
#pragma unroll
    for (int j = 0; j < 1 + S_; ++j) se += expf(sims[j] - m);
    const float lse = m + logf(se);
    local = -(sims[0] - lse);                // -log_softmax[...,0]
  }

  // ---- wave-0 reduce + plain per-block store (no same-address atomic) ----
#pragma unroll
  for (int off = 32; off >= 1; off >>= 1)
    local += __shfl_xor(local, off, 64);
  if (threadIdx.x == 0)
    partials[n] = local;
}

__global__ __launch_bounds__(256) void phoneme_ssl_reduce_kernel(
    const float* __restrict__ partials, float* __restrict__ loss_out) {
  float acc = 0.f;
  for (int i = threadIdx.x; i < NSEG; i += 256) acc += partials[i];
#pragma unroll
  for (int off = 32; off >= 1; off >>= 1)
    acc += __shfl_xor(acc, off, 64);
  __shared__ float ws[4];
  if ((threadIdx.x & 63) == 0) ws[threadIdx.x >> 6] = acc;
  __syncthreads();
  if (threadIdx.x == 0)
    loss_out[0] = (ws[0] + ws[1] + ws[2] + ws[3]) * (1.0f / (float)(NSEG * NPOS));
}

extern "C" void kernel_launch(void* const* d_in, const int* in_sizes, int n_in,
                              void* d_out, int out_size, void* d_ws, size_t ws_size,
                              hipStream_t stream) {
  const float* out_t    = (const float*)d_in[0];
  const int* batch_idx  = (const int*)d_in[1];
  const int* time_idx   = (const int*)d_in[2];
  const int* neg_idx    = (const int*)d_in[3];
  float* loss_out       = (float*)d_out;
  float* partials       = (float*)d_ws;      // NSEG floats, fully overwritten each call

  phoneme_ssl_seg_kernel<<<NSEG, 256, 0, stream>>>(
      out_t, batch_idx, time_idx, neg_idx, partials);
  phoneme_ssl_reduce_kernel<<<1, 256, 0, stream>>>(partials, loss_out);
}